// Round 4
// baseline (323.343 us; speedup 1.0000x reference)
//
#include <hip/hip_runtime.h>
#include <hip/hip_bf16.h>
#include <cstdint>
#include <cstddef>

// Problem constants
#define S_LEN 2048
#define DMODEL 2048
#define NHEADS 8
#define DHEAD 128
#define INNER_DIM 1024
#define BATCH 2

typedef __bf16 bf16;
typedef __bf16 bf16x8 __attribute__((ext_vector_type(8)));
typedef __bf16 bf16x4 __attribute__((ext_vector_type(4)));
typedef float f32x4 __attribute__((ext_vector_type(4)));

__device__ __forceinline__ void gload_lds16(const void* g, void* l) {
  __builtin_amdgcn_global_load_lds(
      (const __attribute__((address_space(1))) void*)g,
      (__attribute__((address_space(3))) void*)l, 16, 0, 0);
}

__device__ __forceinline__ float sigmoidf_(float x) {
  return 1.0f / (1.0f + expf(-x));
}

// ---------------------------------------------------------------------------
// Convert fp32 weights -> bf16 (Wq, Wk, Wv laid out contiguously, then Wo).
// ---------------------------------------------------------------------------
__global__ __launch_bounds__(256) void convert_w_kernel(
    const float* __restrict__ wq, const float* __restrict__ wk,
    const float* __restrict__ wv, const float* __restrict__ wo,
    bf16* __restrict__ wqkvb, bf16* __restrict__ wob) {
  size_t i4 = ((size_t)blockIdx.x * 256 + threadIdx.x) * 4;
  const float* src;
  bf16* dst;
  size_t off;
  if (i4 < 2097152UL)       { src = wq; dst = wqkvb;           off = i4; }
  else if (i4 < 4194304UL)  { src = wk; dst = wqkvb + 2097152; off = i4 - 2097152UL; }
  else if (i4 < 6291456UL)  { src = wv; dst = wqkvb + 4194304; off = i4 - 4194304UL; }
  else                      { src = wo; dst = wob;             off = i4 - 6291456UL; }
  float4 v = *(const float4*)(src + off);
  bf16x4 o;
  o[0] = (bf16)v.x; o[1] = (bf16)v.y; o[2] = (bf16)v.z; o[3] = (bf16)v.w;
  *(bf16x4*)(dst + off) = o;
}

// ---------------------------------------------------------------------------
// Per-head alpha.
// ---------------------------------------------------------------------------
__global__ __launch_bounds__(64) void alpha_kernel(
    const float* __restrict__ alpha_log, float* __restrict__ la_mean,
    float* __restrict__ la_d) {
  int h = blockIdx.x;
  int lane = threadIdx.x;
  float a1 = sigmoidf_(alpha_log[h * 128 + lane]);
  float a2 = sigmoidf_(alpha_log[h * 128 + 64 + lane]);
  la_d[h * 128 + lane] = logf(a1);
  la_d[h * 128 + 64 + lane] = logf(a2);
  float s = a1 + a2;
  for (int off = 32; off; off >>= 1) s += __shfl_down(s, off);
  if (lane == 0) la_mean[h] = logf(fmaxf(s * (1.0f / 128.0f), 1e-6f));
}

// ---------------------------------------------------------------------------
// beta[n,h] = sigmoid(x[n,:].Wb[h,:] + bb[h]); also emits xb = bf16(x).
// ---------------------------------------------------------------------------
__global__ __launch_bounds__(64) void beta_xb_kernel(
    const float* __restrict__ x, const float* __restrict__ Wb,
    const float* __restrict__ bbias, float* __restrict__ beta,
    bf16* __restrict__ xb) {
  int n = blockIdx.x;
  int lane = threadIdx.x;
  float acc[8];
#pragma unroll
  for (int h = 0; h < 8; h++) acc[h] = 0.0f;
  const float4* x4 = (const float4*)(x + (size_t)n * DMODEL);
  bf16* xbr = xb + (size_t)n * DMODEL;
  for (int d4 = lane; d4 < DMODEL / 4; d4 += 64) {
    float4 xv = x4[d4];
    bf16x4 o;
    o[0] = (bf16)xv.x; o[1] = (bf16)xv.y; o[2] = (bf16)xv.z; o[3] = (bf16)xv.w;
    *(bf16x4*)(xbr + d4 * 4) = o;
#pragma unroll
    for (int h = 0; h < 8; h++) {
      float4 wv = ((const float4*)(Wb + (size_t)h * DMODEL))[d4];
      acc[h] += xv.x * wv.x + xv.y * wv.y + xv.z * wv.z + xv.w * wv.w;
    }
  }
#pragma unroll
  for (int off = 32; off; off >>= 1)
#pragma unroll
    for (int h = 0; h < 8; h++) acc[h] += __shfl_down(acc[h], off);
  if (lane == 0) {
#pragma unroll
    for (int h = 0; h < 8; h++)
      beta[(size_t)n * 8 + h] = sigmoidf_(acc[h] + bbias[h]);
  }
}

// ---------------------------------------------------------------------------
// bf16 NT GEMM, XOR-swizzled LDS + XCD-aware tile swizzle.
// XCD swizzle: linear id -> (xcd = id&7, s = id>>3). Each XCD gets a compact
// supertile region (x-span gridDim.x/4, y-span gridDim.y/2, all z) so its
// 4 MB L2 sees high stripe reuse instead of streaming the whole A matrix.
// Requires gridDim.x % 4 == 0 and gridDim.y % 2 == 0.
// obf: 1 -> store bf16, 0 -> store f32.
// ---------------------------------------------------------------------------
__global__ __launch_bounds__(256) void gemm_bt_kernel(
    const bf16* __restrict__ A, const bf16* __restrict__ Bm, void* Cv, int K,
    int N, size_t strideB, size_t strideC, int obf) {
  // ---- XCD-aware tile remap (bijective) ----
  const int id = blockIdx.x + gridDim.x * (blockIdx.y + gridDim.y * blockIdx.z);
  const int xcd = id & 7;
  const int s = id >> 3;
  const int xs = gridDim.x >> 2;   // tiles per x-group
  const int ys = gridDim.y >> 1;   // tiles per y-group
  const int perz = xs * ys;
  const int z = s / perz;
  const int r = s - z * perz;
  const int tx = (xcd & 3) * xs + (r % xs);
  const int ty = (xcd >> 2) * ys + (r / xs);
  const int tile_n = tx * 128;
  const int tile_m = ty * 128;

  const bf16* Bp = Bm + (size_t)z * strideB;
  const int tid = threadIdx.x;
  const int lane = tid & 63;
  const int wv = tid >> 6;

  __shared__ bf16 As[128 * 32];
  __shared__ bf16 Bs[128 * 32];

  f32x4 acc[4][4];
#pragma unroll
  for (int i = 0; i < 4; i++)
#pragma unroll
    for (int j = 0; j < 4; j++) acc[i][j] = (f32x4){0.f, 0.f, 0.f, 0.f};

  const int wm = (wv >> 1) * 64;
  const int wn = (wv & 1) * 64;
  const int lr = lane & 15;
  const int kq = lane >> 4;
  const int swzA = ((wm + lr) >> 1) & 3;
  const int swzB = ((wn + lr) >> 1) & 3;
  const int kA = (kq ^ swzA) * 8;
  const int kB = (kq ^ swzB) * 8;

  const int ar = wv * 32 + (lane >> 2);
  const int g = ((lane & 3) ^ ((ar >> 1) & 3)) * 8;
  const bf16* Ag = A + (size_t)(tile_m + ar) * K + g;
  const bf16* Bg = Bp + (size_t)(tile_n + ar) * K + g;
  bf16* AsW = &As[wv * 1024];
  bf16* BsW = &Bs[wv * 1024];

  for (int k0 = 0; k0 < K; k0 += 32) {
    gload_lds16(Ag + k0, AsW);
    gload_lds16(Ag + (size_t)16 * K + k0, AsW + 512);
    gload_lds16(Bg + k0, BsW);
    gload_lds16(Bg + (size_t)16 * K + k0, BsW + 512);
    __syncthreads();
    bf16x8 af[4], bfr[4];
#pragma unroll
    for (int mi = 0; mi < 4; mi++)
      af[mi] = *(const bf16x8*)&As[(wm + mi * 16 + lr) * 32 + kA];
#pragma unroll
    for (int ni = 0; ni < 4; ni++)
      bfr[ni] = *(const bf16x8*)&Bs[(wn + ni * 16 + lr) * 32 + kB];
#pragma unroll
    for (int mi = 0; mi < 4; mi++)
#pragma unroll
      for (int ni = 0; ni < 4; ni++)
        acc[mi][ni] = __builtin_amdgcn_mfma_f32_16x16x32_bf16(
            af[mi], bfr[ni], acc[mi][ni], 0, 0, 0);
    __syncthreads();
  }

  const int crow0 = tile_m + wm + (lane >> 4) * 4;
  const int ccol = tile_n + wn + (lane & 15);
  if (obf) {
    bf16* Cb = (bf16*)Cv + (size_t)z * strideC;
#pragma unroll
    for (int mi = 0; mi < 4; mi++)
#pragma unroll
      for (int ni = 0; ni < 4; ni++)
#pragma unroll
        for (int r2 = 0; r2 < 4; r2++)
          Cb[(size_t)(crow0 + mi * 16 + r2) * N + ccol + ni * 16] =
              (bf16)acc[mi][ni][r2];
  } else {
    float* Cf = (float*)Cv + (size_t)z * strideC;
#pragma unroll
    for (int mi = 0; mi < 4; mi++)
#pragma unroll
      for (int ni = 0; ni < 4; ni++)
#pragma unroll
        for (int r2 = 0; r2 < 4; r2++)
          Cf[(size_t)(crow0 + mi * 16 + r2) * N + ccol + ni * 16] =
              acc[mi][ni][r2];
  }
}

// ---------------------------------------------------------------------------
// RoPE in place on bf16 q and k.
// ---------------------------------------------------------------------------
__global__ __launch_bounds__(256) void rope_kernel(bf16* __restrict__ q,
                                                   bf16* __restrict__ k) {
  int idx = blockIdx.x * 256 + threadIdx.x;  // < 524288
  int j0 = (idx & 15) * 4;
  int nh = idx >> 4;  // n*8 + h, n < 4096
  int s = (nh >> 3) & (S_LEN - 1);
  size_t base = (size_t)nh * 128 + j0;
  bf16x4 qa = *(bf16x4*)&q[base], qb = *(bf16x4*)&q[base + 64];
  bf16x4 ka = *(bf16x4*)&k[base], kb = *(bf16x4*)&k[base + 64];
#pragma unroll
  for (int jj = 0; jj < 4; jj++) {
    float inv = expf(-(float)(j0 + jj) * (9.210340371976184f / 64.0f));
    float f = (float)s * inv;
    float sn, c;
    sincosf(f, &sn, &c);
    float q1 = (float)qa[jj], q2 = (float)qb[jj];
    qa[jj] = (bf16)(q1 * c - q2 * sn);
    qb[jj] = (bf16)(q2 * c + q1 * sn);
    float k1 = (float)ka[jj], k2 = (float)kb[jj];
    ka[jj] = (bf16)(k1 * c - k2 * sn);
    kb[jj] = (bf16)(k2 * c + k1 * sn);
  }
  *(bf16x4*)&q[base] = qa;
  *(bf16x4*)&q[base + 64] = qb;
  *(bf16x4*)&k[base] = ka;
  *(bf16x4*)&k[base + 64] = kb;
}

// ---------------------------------------------------------------------------
// Banded decay attention (window 64), bf16 inputs staged to f32 LDS.
// ---------------------------------------------------------------------------
__global__ __launch_bounds__(256) void attn_kernel(
    const bf16* __restrict__ q, const bf16* __restrict__ k,
    const bf16* __restrict__ v, const float* __restrict__ beta,
    const float* __restrict__ la_mean, bf16* __restrict__ outb) {
  const int s0 = blockIdx.x * 64;
  const int h = blockIdx.y;
  const int b = blockIdx.z;
  const int tid = threadIdx.x;

  __shared__ float qs[64][132];
  __shared__ float ks[32][132];
  __shared__ float vs[32][128];
  __shared__ float wsm[64][33];
  __shared__ float betas[32];

  const int s_l = tid >> 2;
  const int qtr = tid & 3;
  const int s_g = s0 + s_l;
  const float la = la_mean[h];
  const size_t bh_off = ((size_t)b * S_LEN) * INNER_DIM + (size_t)h * 128;

  for (int u = tid; u < 64 * 16; u += 256) {
    int r = u >> 4, c8 = (u & 15) * 8;
    bf16x8 t = *(const bf16x8*)&q[bh_off + (size_t)(s0 + r) * INNER_DIM + c8];
#pragma unroll
    for (int j = 0; j < 8; j++) qs[r][c8 + j] = (float)t[j];
  }

  float acc[32];
#pragma unroll
  for (int i = 0; i < 32; i++) acc[i] = 0.0f;

  for (int tb = s0 - 64; tb <= s0 + 32; tb += 32) {
    __syncthreads();
    for (int u = tid; u < 32 * 16; u += 256) {
      int r = u >> 4, c8 = (u & 15) * 8;
      int t = tb + r;
      if (t >= 0) {
        bf16x8 kv = *(const bf16x8*)&k[bh_off + (size_t)t * INNER_DIM + c8];
        bf16x8 vv = *(const bf16x8*)&v[bh_off + (size_t)t * INNER_DIM + c8];
#pragma unroll
        for (int j = 0; j < 8; j++) {
          ks[r][c8 + j] = (float)kv[j];
          vs[r][c8 + j] = (float)vv[j];
        }
      } else {
#pragma unroll
        for (int j = 0; j < 8; j++) {
          ks[r][c8 + j] = 0.0f;
          vs[r][c8 + j] = 0.0f;
        }
      }
    }
    if (tid < 32) {
      int t = tb + tid;
      betas[tid] = (t >= 0) ? beta[((size_t)b * S_LEN + t) * 8 + h] : 0.0f;
    }
    __syncthreads();
#pragma unroll
    for (int jj = 0; jj < 8; jj++) {
      int tl = qtr * 8 + jj;
      int t = tb + tl;
      int td = s_g - t;
      float w = 0.0f;
      if (t >= 0 && td >= 0 && td < 64) {
        float dot = 0.0f;
#pragma unroll
        for (int d = 0; d < 128; d += 4) {
          float4 qv = *(const float4*)&qs[s_l][d];
          float4 kv = *(const float4*)&ks[tl][d];
          dot = fmaf(qv.x, kv.x,
                fmaf(qv.y, kv.y, fmaf(qv.z, kv.z, fmaf(qv.w, kv.w, dot))));
        }
        w = dot * __expf((float)td * la) * betas[tl];
      }
      wsm[s_l][tl] = w;
    }
    __syncthreads();
    for (int tl = 0; tl < 32; tl++) {
      float w = wsm[s_l][tl];
      if (w != 0.0f) {
#pragma unroll
        for (int e4 = 0; e4 < 32; e4 += 4) {
          float4 vv = *(const float4*)&vs[tl][qtr * 32 + e4];
          acc[e4 + 0] = fmaf(w, vv.x, acc[e4 + 0]);
          acc[e4 + 1] = fmaf(w, vv.y, acc[e4 + 1]);
          acc[e4 + 2] = fmaf(w, vv.z, acc[e4 + 2]);
          acc[e4 + 3] = fmaf(w, vv.w, acc[e4 + 3]);
        }
      }
    }
  }
  size_t ob = bh_off + (size_t)s_g * INNER_DIM + qtr * 32;
#pragma unroll
  for (int e4 = 0; e4 < 32; e4 += 4) {
    bf16x4 o;
    o[0] = (bf16)acc[e4 + 0];
    o[1] = (bf16)acc[e4 + 1];
    o[2] = (bf16)acc[e4 + 2];
    o[3] = (bf16)acc[e4 + 3];
    *(bf16x4*)(outb + ob + e4) = o;
  }
}

// ---------------------------------------------------------------------------
// Stage 1: partial state per 32-step chunk (bf16 k/v inputs), no atomics.
// ---------------------------------------------------------------------------
__global__ __launch_bounds__(256) void state_partial_kernel(
    const bf16* __restrict__ k, const bf16* __restrict__ v,
    const float* __restrict__ beta, const float* __restrict__ la_d,
    float* __restrict__ part) {
  const int bh = blockIdx.x;
  const int chunk = blockIdx.y;
  const int b = bh >> 3, h = bh & 7;
  const int t0 = S_LEN - 512 + chunk * 32;
  const int tid = threadIdx.x;
  const int d = tid >> 1;
  const int eh = (tid & 1) * 64;

  __shared__ float ks[32][128];
  __shared__ float vsm[32][128];
  __shared__ float bs[32];

  const size_t bh_off = ((size_t)b * S_LEN) * INNER_DIM + (size_t)h * 128;
  for (int u = tid; u < 32 * 16; u += 256) {
    int r = u >> 4, c8 = (u & 15) * 8;
    bf16x8 kv = *(const bf16x8*)&k[bh_off + (size_t)(t0 + r) * INNER_DIM + c8];
    bf16x8 vv = *(const bf16x8*)&v[bh_off + (size_t)(t0 + r) * INNER_DIM + c8];
#pragma unroll
    for (int j = 0; j < 8; j++) {
      ks[r][c8 + j] = (float)kv[j];
      vsm[r][c8 + j] = (float)vv[j];
    }
  }
  if (tid < 32) bs[tid] = beta[((size_t)b * S_LEN + t0 + tid) * 8 + h];
  __syncthreads();

  const float lad = la_d[h * 128 + d];
  float acc[64];
#pragma unroll
  for (int e = 0; e < 64; e++) acc[e] = 0.0f;

  for (int tl = 0; tl < 32; tl++) {
    int m = (S_LEN - 1) - (t0 + tl);
    float f = __expf((float)m * lad);
    float coef = bs[tl] * ks[tl][d] * f;
    if (coef != 0.0f) {
#pragma unroll
      for (int e = 0; e < 64; e += 4) {
        float4 vv = *(const float4*)&vsm[tl][eh + e];
        acc[e + 0] = fmaf(coef, vv.x, acc[e + 0]);
        acc[e + 1] = fmaf(coef, vv.y, acc[e + 1]);
        acc[e + 2] = fmaf(coef, vv.z, acc[e + 2]);
        acc[e + 3] = fmaf(coef, vv.w, acc[e + 3]);
      }
    }
  }
  float* pp = part + (((size_t)chunk * 16 + bh) * 16384 + (size_t)d * 128 + eh);
#pragma unroll
  for (int e = 0; e < 64; e += 4) {
    float4 o = {acc[e + 0], acc[e + 1], acc[e + 2], acc[e + 3]};
    *(float4*)&pp[e] = o;
  }
}

// ---------------------------------------------------------------------------
// Stage 2: sum the 16 chunk partials into the final state.
// ---------------------------------------------------------------------------
__global__ __launch_bounds__(256) void state_reduce_kernel(
    const float* __restrict__ part, float* __restrict__ state) {
  size_t off = ((size_t)blockIdx.x * 256 + threadIdx.x) * 4;
  float4 s = {0.f, 0.f, 0.f, 0.f};
#pragma unroll
  for (int c = 0; c < 16; c++) {
    float4 p = *(const float4*)&part[(size_t)c * 262144 + off];
    s.x += p.x; s.y += p.y; s.z += p.z; s.w += p.w;
  }
  *(float4*)&state[off] = s;
}

// ---------------------------------------------------------------------------
extern "C" void kernel_launch(void* const* d_in, const int* in_sizes, int n_in,
                              void* d_out, int out_size, void* d_ws,
                              size_t ws_size, hipStream_t stream) {
  const float* x = (const float*)d_in[0];
  const float* Wq = (const float*)d_in[1];
  const float* Wk = (const float*)d_in[2];
  const float* Wv = (const float*)d_in[3];
  const float* Wo = (const float*)d_in[4];
  const float* Wb = (const float*)d_in[5];
  const float* bb = (const float*)d_in[6];
  const float* alog = (const float*)d_in[7];
  float* out = (float*)d_out;

  char* ws = (char*)d_ws;
  bf16* xb = (bf16*)(ws);                      // 16 MB (8M elems)
  float* part = (float*)(ws);                  // reuses xb after QKV GEMM
  bf16* wqkvb = (bf16*)(ws + 16777216UL);      // 12 MB (3 x 2,097,152 elems)
  bf16* wob = (bf16*)(ws + 29360128UL);        // 4 MB
  bf16* q = (bf16*)(ws + 33554432UL);          // 8 MB (4,194,304 elems)
  bf16* kk = (bf16*)(ws + 41943040UL);         // 8 MB
  bf16* vv = (bf16*)(ws + 50331648UL);         // 8 MB
  bf16* attnb = (bf16*)(ws + 58720256UL);      // 8 MB
  float* beta = (float*)(ws + 67108864UL);     // 128 KB
  float* la_mean = (float*)(ws + 67239936UL);  // 32 B
  float* la_d = (float*)(ws + 67239968UL);     // 4 KB

  convert_w_kernel<<<8192, 256, 0, stream>>>(Wq, Wk, Wv, Wo, wqkvb, wob);
  alpha_kernel<<<8, 64, 0, stream>>>(alog, la_mean, la_d);
  beta_xb_kernel<<<BATCH * S_LEN, 64, 0, stream>>>(x, Wb, bb, beta, xb);
  // fused QKV GEMM -> bf16 q/kk/vv (contiguous, strideC = 4,194,304 elems)
  gemm_bt_kernel<<<dim3(INNER_DIM / 128, (BATCH * S_LEN) / 128, 3), 256, 0,
                   stream>>>(xb, wqkvb, q, DMODEL, INNER_DIM, 2097152UL,
                             4194304UL, 1);
  rope_kernel<<<2048, 256, 0, stream>>>(q, kk);
  attn_kernel<<<dim3(S_LEN / 64, NHEADS, BATCH), 256, 0, stream>>>(
      q, kk, vv, beta, la_mean, attnb);
  state_partial_kernel<<<dim3(16, 16), 256, 0, stream>>>(kk, vv, beta, la_d,
                                                         part);
  state_reduce_kernel<<<256, 256, 0, stream>>>(part, out + 8388608);
  gemm_bt_kernel<<<dim3(DMODEL / 128, (BATCH * S_LEN) / 128, 1), 256, 0,
                   stream>>>(attnb, wob, out, INNER_DIM, DMODEL, 0, 0, 0);
}

// Round 5
// 321.205 us; speedup vs baseline: 1.0067x; 1.0067x over previous
//
#include <hip/hip_runtime.h>
#include <hip/hip_bf16.h>
#include <cstdint>
#include <cstddef>

// Problem constants
#define S_LEN 2048
#define DMODEL 2048
#define NHEADS 8
#define DHEAD 128
#define INNER_DIM 1024
#define BATCH 2

typedef __bf16 bf16;
typedef __bf16 bf16x8 __attribute__((ext_vector_type(8)));
typedef __bf16 bf16x4 __attribute__((ext_vector_type(4)));
typedef float f32x4 __attribute__((ext_vector_type(4)));

__device__ __forceinline__ void gload_lds16(const void* g, void* l) {
  __builtin_amdgcn_global_load_lds(
      (const __attribute__((address_space(1))) void*)g,
      (__attribute__((address_space(3))) void*)l, 16, 0, 0);
}

__device__ __forceinline__ float sigmoidf_(float x) {
  return 1.0f / (1.0f + expf(-x));
}

// ---------------------------------------------------------------------------
// Convert fp32 weights -> bf16 (Wq, Wk, Wv laid out contiguously, then Wo).
// ---------------------------------------------------------------------------
__global__ __launch_bounds__(256) void convert_w_kernel(
    const float* __restrict__ wq, const float* __restrict__ wk,
    const float* __restrict__ wv, const float* __restrict__ wo,
    bf16* __restrict__ wqkvb, bf16* __restrict__ wob) {
  size_t i4 = ((size_t)blockIdx.x * 256 + threadIdx.x) * 4;
  const float* src;
  bf16* dst;
  size_t off;
  if (i4 < 2097152UL)       { src = wq; dst = wqkvb;           off = i4; }
  else if (i4 < 4194304UL)  { src = wk; dst = wqkvb + 2097152; off = i4 - 2097152UL; }
  else if (i4 < 6291456UL)  { src = wv; dst = wqkvb + 4194304; off = i4 - 4194304UL; }
  else                      { src = wo; dst = wob;             off = i4 - 6291456UL; }
  float4 v = *(const float4*)(src + off);
  bf16x4 o;
  o[0] = (bf16)v.x; o[1] = (bf16)v.y; o[2] = (bf16)v.z; o[3] = (bf16)v.w;
  *(bf16x4*)(dst + off) = o;
}

// ---------------------------------------------------------------------------
// Per-head alpha.
// ---------------------------------------------------------------------------
__global__ __launch_bounds__(64) void alpha_kernel(
    const float* __restrict__ alpha_log, float* __restrict__ la_mean,
    float* __restrict__ la_d) {
  int h = blockIdx.x;
  int lane = threadIdx.x;
  float a1 = sigmoidf_(alpha_log[h * 128 + lane]);
  float a2 = sigmoidf_(alpha_log[h * 128 + 64 + lane]);
  la_d[h * 128 + lane] = logf(a1);
  la_d[h * 128 + 64 + lane] = logf(a2);
  float s = a1 + a2;
  for (int off = 32; off; off >>= 1) s += __shfl_down(s, off);
  if (lane == 0) la_mean[h] = logf(fmaxf(s * (1.0f / 128.0f), 1e-6f));
}

// ---------------------------------------------------------------------------
// beta[n,h] = sigmoid(x[n,:].Wb[h,:] + bb[h]); also emits xb = bf16(x).
// ---------------------------------------------------------------------------
__global__ __launch_bounds__(64) void beta_xb_kernel(
    const float* __restrict__ x, const float* __restrict__ Wb,
    const float* __restrict__ bbias, float* __restrict__ beta,
    bf16* __restrict__ xb) {
  int n = blockIdx.x;
  int lane = threadIdx.x;
  float acc[8];
#pragma unroll
  for (int h = 0; h < 8; h++) acc[h] = 0.0f;
  const float4* x4 = (const float4*)(x + (size_t)n * DMODEL);
  bf16* xbr = xb + (size_t)n * DMODEL;
  for (int d4 = lane; d4 < DMODEL / 4; d4 += 64) {
    float4 xv = x4[d4];
    bf16x4 o;
    o[0] = (bf16)xv.x; o[1] = (bf16)xv.y; o[2] = (bf16)xv.z; o[3] = (bf16)xv.w;
    *(bf16x4*)(xbr + d4 * 4) = o;
#pragma unroll
    for (int h = 0; h < 8; h++) {
      float4 wv = ((const float4*)(Wb + (size_t)h * DMODEL))[d4];
      acc[h] += xv.x * wv.x + xv.y * wv.y + xv.z * wv.z + xv.w * wv.w;
    }
  }
#pragma unroll
  for (int off = 32; off; off >>= 1)
#pragma unroll
    for (int h = 0; h < 8; h++) acc[h] += __shfl_down(acc[h], off);
  if (lane == 0) {
#pragma unroll
    for (int h = 0; h < 8; h++)
      beta[(size_t)n * 8 + h] = sigmoidf_(acc[h] + bbias[h]);
  }
}

// ---------------------------------------------------------------------------
// bf16 NT GEMM, BK=64 K-loop (half the barriers of BK=32), XOR-swizzled LDS,
// XCD-aware tile swizzle.
// LDS row = 64 bf16 (128 B) = 8 x 16B blocks; physical block p of row r holds
// global k-block p ^ (r & 7). Staging swizzle is lane-only ((l&7)^(l>>3));
// read swizzle is lr&7 (wm/wn/mi/ni are all ≡0 mod 8 in the row index).
// Requires gridDim.x % 4 == 0, gridDim.y % 2 == 0, K % 64 == 0.
// obf: 1 -> store bf16, 0 -> store f32.
// ---------------------------------------------------------------------------
__global__ __launch_bounds__(256) void gemm_bt_kernel(
    const bf16* __restrict__ A, const bf16* __restrict__ Bm, void* Cv, int K,
    int N, size_t strideB, size_t strideC, int obf) {
  // ---- XCD-aware tile remap (bijective) ----
  const int id = blockIdx.x + gridDim.x * (blockIdx.y + gridDim.y * blockIdx.z);
  const int xcd = id & 7;
  const int s = id >> 3;
  const int xs = gridDim.x >> 2;   // tiles per x-group
  const int ys = gridDim.y >> 1;   // tiles per y-group
  const int perz = xs * ys;
  const int z = s / perz;
  const int r = s - z * perz;
  const int tx = (xcd & 3) * xs + (r % xs);
  const int ty = (xcd >> 2) * ys + (r / xs);
  const int tile_n = tx * 128;
  const int tile_m = ty * 128;

  const bf16* Bp = Bm + (size_t)z * strideB;
  const int tid = threadIdx.x;
  const int lane = tid & 63;
  const int wv = tid >> 6;

  __shared__ bf16 As[128 * 64];
  __shared__ bf16 Bs[128 * 64];

  f32x4 acc[4][4];
#pragma unroll
  for (int i = 0; i < 4; i++)
#pragma unroll
    for (int j = 0; j < 4; j++) acc[i][j] = (f32x4){0.f, 0.f, 0.f, 0.f};

  const int wm = (wv >> 1) * 64;
  const int wn = (wv & 1) * 64;
  const int lr = lane & 15;
  const int kq = lane >> 4;
  const int swz = lr & 7;           // row&7 for every fragment row we read
  const int kA0 = (kq ^ swz) * 8;   // sub-tile s: kA0 ^ (s*32)

  // staging: issue j covers rows wv*32 + j*8 .. +8; lane l -> row +(l>>3),
  // physical 16B block p = l&7 holding global block g = p ^ (l>>3).
  const int srow = wv * 32 + (lane >> 3);
  const int g = ((lane & 7) ^ (lane >> 3)) * 8;
  const bf16* Ag = A + (size_t)(tile_m + srow) * K + g;
  const bf16* Bg = Bp + (size_t)(tile_n + srow) * K + g;
  bf16* AsW = &As[wv * 2048];
  bf16* BsW = &Bs[wv * 2048];

  for (int k0 = 0; k0 < K; k0 += 64) {
#pragma unroll
    for (int j = 0; j < 4; j++) {
      gload_lds16(Ag + (size_t)j * 8 * K + k0, AsW + j * 512);
      gload_lds16(Bg + (size_t)j * 8 * K + k0, BsW + j * 512);
    }
    __syncthreads();
#pragma unroll
    for (int sub = 0; sub < 2; sub++) {
      const int ka = kA0 ^ (sub * 32);
      bf16x8 af[4], bfr[4];
#pragma unroll
      for (int mi = 0; mi < 4; mi++)
        af[mi] = *(const bf16x8*)&As[(wm + mi * 16 + lr) * 64 + ka];
#pragma unroll
      for (int ni = 0; ni < 4; ni++)
        bfr[ni] = *(const bf16x8*)&Bs[(wn + ni * 16 + lr) * 64 + ka];
#pragma unroll
      for (int mi = 0; mi < 4; mi++)
#pragma unroll
        for (int ni = 0; ni < 4; ni++)
          acc[mi][ni] = __builtin_amdgcn_mfma_f32_16x16x32_bf16(
              af[mi], bfr[ni], acc[mi][ni], 0, 0, 0);
    }
    __syncthreads();
  }

  const int crow0 = tile_m + wm + (lane >> 4) * 4;
  const int ccol = tile_n + wn + (lane & 15);
  if (obf) {
    bf16* Cb = (bf16*)Cv + (size_t)z * strideC;
#pragma unroll
    for (int mi = 0; mi < 4; mi++)
#pragma unroll
      for (int ni = 0; ni < 4; ni++)
#pragma unroll
        for (int r2 = 0; r2 < 4; r2++)
          Cb[(size_t)(crow0 + mi * 16 + r2) * N + ccol + ni * 16] =
              (bf16)acc[mi][ni][r2];
  } else {
    float* Cf = (float*)Cv + (size_t)z * strideC;
#pragma unroll
    for (int mi = 0; mi < 4; mi++)
#pragma unroll
      for (int ni = 0; ni < 4; ni++)
#pragma unroll
        for (int r2 = 0; r2 < 4; r2++)
          Cf[(size_t)(crow0 + mi * 16 + r2) * N + ccol + ni * 16] =
              acc[mi][ni][r2];
  }
}

// ---------------------------------------------------------------------------
// RoPE in place on bf16 q and k.
// ---------------------------------------------------------------------------
__global__ __launch_bounds__(256) void rope_kernel(bf16* __restrict__ q,
                                                   bf16* __restrict__ k) {
  int idx = blockIdx.x * 256 + threadIdx.x;  // < 524288
  int j0 = (idx & 15) * 4;
  int nh = idx >> 4;  // n*8 + h, n < 4096
  int s = (nh >> 3) & (S_LEN - 1);
  size_t base = (size_t)nh * 128 + j0;
  bf16x4 qa = *(bf16x4*)&q[base], qb = *(bf16x4*)&q[base + 64];
  bf16x4 ka = *(bf16x4*)&k[base], kb = *(bf16x4*)&k[base + 64];
#pragma unroll
  for (int jj = 0; jj < 4; jj++) {
    float inv = expf(-(float)(j0 + jj) * (9.210340371976184f / 64.0f));
    float f = (float)s * inv;
    float sn, c;
    sincosf(f, &sn, &c);
    float q1 = (float)qa[jj], q2 = (float)qb[jj];
    qa[jj] = (bf16)(q1 * c - q2 * sn);
    qb[jj] = (bf16)(q2 * c + q1 * sn);
    float k1 = (float)ka[jj], k2 = (float)kb[jj];
    ka[jj] = (bf16)(k1 * c - k2 * sn);
    kb[jj] = (bf16)(k2 * c + k1 * sn);
  }
  *(bf16x4*)&q[base] = qa;
  *(bf16x4*)&q[base + 64] = qb;
  *(bf16x4*)&k[base] = ka;
  *(bf16x4*)&k[base + 64] = kb;
}

// ---------------------------------------------------------------------------
// Banded decay attention (window 64), bf16 inputs staged to f32 LDS.
// ---------------------------------------------------------------------------
__global__ __launch_bounds__(256) void attn_kernel(
    const bf16* __restrict__ q, const bf16* __restrict__ k,
    const bf16* __restrict__ v, const float* __restrict__ beta,
    const float* __restrict__ la_mean, bf16* __restrict__ outb) {
  const int s0 = blockIdx.x * 64;
  const int h = blockIdx.y;
  const int b = blockIdx.z;
  const int tid = threadIdx.x;

  __shared__ float qs[64][132];
  __shared__ float ks[32][132];
  __shared__ float vs[32][128];
  __shared__ float wsm[64][33];
  __shared__ float betas[32];

  const int s_l = tid >> 2;
  const int qtr = tid & 3;
  const int s_g = s0 + s_l;
  const float la = la_mean[h];
  const size_t bh_off = ((size_t)b * S_LEN) * INNER_DIM + (size_t)h * 128;

  for (int u = tid; u < 64 * 16; u += 256) {
    int r = u >> 4, c8 = (u & 15) * 8;
    bf16x8 t = *(const bf16x8*)&q[bh_off + (size_t)(s0 + r) * INNER_DIM + c8];
#pragma unroll
    for (int j = 0; j < 8; j++) qs[r][c8 + j] = (float)t[j];
  }

  float acc[32];
#pragma unroll
  for (int i = 0; i < 32; i++) acc[i] = 0.0f;

  for (int tb = s0 - 64; tb <= s0 + 32; tb += 32) {
    __syncthreads();
    for (int u = tid; u < 32 * 16; u += 256) {
      int r = u >> 4, c8 = (u & 15) * 8;
      int t = tb + r;
      if (t >= 0) {
        bf16x8 kv = *(const bf16x8*)&k[bh_off + (size_t)t * INNER_DIM + c8];
        bf16x8 vv = *(const bf16x8*)&v[bh_off + (size_t)t * INNER_DIM + c8];
#pragma unroll
        for (int j = 0; j < 8; j++) {
          ks[r][c8 + j] = (float)kv[j];
          vs[r][c8 + j] = (float)vv[j];
        }
      } else {
#pragma unroll
        for (int j = 0; j < 8; j++) {
          ks[r][c8 + j] = 0.0f;
          vs[r][c8 + j] = 0.0f;
        }
      }
    }
    if (tid < 32) {
      int t = tb + tid;
      betas[tid] = (t >= 0) ? beta[((size_t)b * S_LEN + t) * 8 + h] : 0.0f;
    }
    __syncthreads();
#pragma unroll
    for (int jj = 0; jj < 8; jj++) {
      int tl = qtr * 8 + jj;
      int t = tb + tl;
      int td = s_g - t;
      float w = 0.0f;
      if (t >= 0 && td >= 0 && td < 64) {
        float dot = 0.0f;
#pragma unroll
        for (int d = 0; d < 128; d += 4) {
          float4 qv = *(const float4*)&qs[s_l][d];
          float4 kv = *(const float4*)&ks[tl][d];
          dot = fmaf(qv.x, kv.x,
                fmaf(qv.y, kv.y, fmaf(qv.z, kv.z, fmaf(qv.w, kv.w, dot))));
        }
        w = dot * __expf((float)td * la) * betas[tl];
      }
      wsm[s_l][tl] = w;
    }
    __syncthreads();
    for (int tl = 0; tl < 32; tl++) {
      float w = wsm[s_l][tl];
      if (w != 0.0f) {
#pragma unroll
        for (int e4 = 0; e4 < 32; e4 += 4) {
          float4 vv = *(const float4*)&vs[tl][qtr * 32 + e4];
          acc[e4 + 0] = fmaf(w, vv.x, acc[e4 + 0]);
          acc[e4 + 1] = fmaf(w, vv.y, acc[e4 + 1]);
          acc[e4 + 2] = fmaf(w, vv.z, acc[e4 + 2]);
          acc[e4 + 3] = fmaf(w, vv.w, acc[e4 + 3]);
        }
      }
    }
  }
  size_t ob = bh_off + (size_t)s_g * INNER_DIM + qtr * 32;
#pragma unroll
  for (int e4 = 0; e4 < 32; e4 += 4) {
    bf16x4 o;
    o[0] = (bf16)acc[e4 + 0];
    o[1] = (bf16)acc[e4 + 1];
    o[2] = (bf16)acc[e4 + 2];
    o[3] = (bf16)acc[e4 + 3];
    *(bf16x4*)(outb + ob + e4) = o;
  }
}

// ---------------------------------------------------------------------------
// Stage 1: partial state per 32-step chunk (bf16 k/v inputs), no atomics.
// ---------------------------------------------------------------------------
__global__ __launch_bounds__(256) void state_partial_kernel(
    const bf16* __restrict__ k, const bf16* __restrict__ v,
    const float* __restrict__ beta, const float* __restrict__ la_d,
    float* __restrict__ part) {
  const int bh = blockIdx.x;
  const int chunk = blockIdx.y;
  const int b = bh >> 3, h = bh & 7;
  const int t0 = S_LEN - 512 + chunk * 32;
  const int tid = threadIdx.x;
  const int d = tid >> 1;
  const int eh = (tid & 1) * 64;

  __shared__ float ks[32][128];
  __shared__ float vsm[32][128];
  __shared__ float bs[32];

  const size_t bh_off = ((size_t)b * S_LEN) * INNER_DIM + (size_t)h * 128;
  for (int u = tid; u < 32 * 16; u += 256) {
    int r = u >> 4, c8 = (u & 15) * 8;
    bf16x8 kv = *(const bf16x8*)&k[bh_off + (size_t)(t0 + r) * INNER_DIM + c8];
    bf16x8 vv = *(const bf16x8*)&v[bh_off + (size_t)(t0 + r) * INNER_DIM + c8];
#pragma unroll
    for (int j = 0; j < 8; j++) {
      ks[r][c8 + j] = (float)kv[j];
      vsm[r][c8 + j] = (float)vv[j];
    }
  }
  if (tid < 32) bs[tid] = beta[((size_t)b * S_LEN + t0 + tid) * 8 + h];
  __syncthreads();

  const float lad = la_d[h * 128 + d];
  float acc[64];
#pragma unroll
  for (int e = 0; e < 64; e++) acc[e] = 0.0f;

  for (int tl = 0; tl < 32; tl++) {
    int m = (S_LEN - 1) - (t0 + tl);
    float f = __expf((float)m * lad);
    float coef = bs[tl] * ks[tl][d] * f;
    if (coef != 0.0f) {
#pragma unroll
      for (int e = 0; e < 64; e += 4) {
        float4 vv = *(const float4*)&vsm[tl][eh + e];
        acc[e + 0] = fmaf(coef, vv.x, acc[e + 0]);
        acc[e + 1] = fmaf(coef, vv.y, acc[e + 1]);
        acc[e + 2] = fmaf(coef, vv.z, acc[e + 2]);
        acc[e + 3] = fmaf(coef, vv.w, acc[e + 3]);
      }
    }
  }
  float* pp = part + (((size_t)chunk * 16 + bh) * 16384 + (size_t)d * 128 + eh);
#pragma unroll
  for (int e = 0; e < 64; e += 4) {
    float4 o = {acc[e + 0], acc[e + 1], acc[e + 2], acc[e + 3]};
    *(float4*)&pp[e] = o;
  }
}

// ---------------------------------------------------------------------------
// Stage 2: sum the 16 chunk partials into the final state.
// ---------------------------------------------------------------------------
__global__ __launch_bounds__(256) void state_reduce_kernel(
    const float* __restrict__ part, float* __restrict__ state) {
  size_t off = ((size_t)blockIdx.x * 256 + threadIdx.x) * 4;
  float4 s = {0.f, 0.f, 0.f, 0.f};
#pragma unroll
  for (int c = 0; c < 16; c++) {
    float4 p = *(const float4*)&part[(size_t)c * 262144 + off];
    s.x += p.x; s.y += p.y; s.z += p.z; s.w += p.w;
  }
  *(float4*)&state[off] = s;
}

// ---------------------------------------------------------------------------
extern "C" void kernel_launch(void* const* d_in, const int* in_sizes, int n_in,
                              void* d_out, int out_size, void* d_ws,
                              size_t ws_size, hipStream_t stream) {
  const float* x = (const float*)d_in[0];
  const float* Wq = (const float*)d_in[1];
  const float* Wk = (const float*)d_in[2];
  const float* Wv = (const float*)d_in[3];
  const float* Wo = (const float*)d_in[4];
  const float* Wb = (const float*)d_in[5];
  const float* bb = (const float*)d_in[6];
  const float* alog = (const float*)d_in[7];
  float* out = (float*)d_out;

  char* ws = (char*)d_ws;
  bf16* xb = (bf16*)(ws);                      // 16 MB (8M elems)
  float* part = (float*)(ws);                  // reuses xb after QKV GEMM
  bf16* wqkvb = (bf16*)(ws + 16777216UL);      // 12 MB (3 x 2,097,152 elems)
  bf16* wob = (bf16*)(ws + 29360128UL);        // 4 MB
  bf16* q = (bf16*)(ws + 33554432UL);          // 8 MB (4,194,304 elems)
  bf16* kk = (bf16*)(ws + 41943040UL);         // 8 MB
  bf16* vv = (bf16*)(ws + 50331648UL);         // 8 MB
  bf16* attnb = (bf16*)(ws + 58720256UL);      // 8 MB
  float* beta = (float*)(ws + 67108864UL);     // 128 KB
  float* la_mean = (float*)(ws + 67239936UL);  // 32 B
  float* la_d = (float*)(ws + 67239968UL);     // 4 KB

  convert_w_kernel<<<8192, 256, 0, stream>>>(Wq, Wk, Wv, Wo, wqkvb, wob);
  alpha_kernel<<<8, 64, 0, stream>>>(alog, la_mean, la_d);
  beta_xb_kernel<<<BATCH * S_LEN, 64, 0, stream>>>(x, Wb, bb, beta, xb);
  // fused QKV GEMM -> bf16 q/kk/vv (contiguous, strideC = 4,194,304 elems)
  gemm_bt_kernel<<<dim3(INNER_DIM / 128, (BATCH * S_LEN) / 128, 3), 256, 0,
                   stream>>>(xb, wqkvb, q, DMODEL, INNER_DIM, 2097152UL,
                             4194304UL, 1);
  rope_kernel<<<2048, 256, 0, stream>>>(q, kk);
  attn_kernel<<<dim3(S_LEN / 64, NHEADS, BATCH), 256, 0, stream>>>(
      q, kk, vv, beta, la_mean, attnb);
  state_partial_kernel<<<dim3(16, 16), 256, 0, stream>>>(kk, vv, beta, la_d,
                                                         part);
  state_reduce_kernel<<<256, 256, 0, stream>>>(part, out + 8388608);
  gemm_bt_kernel<<<dim3(DMODEL / 128, (BATCH * S_LEN) / 128, 1), 256, 0,
                   stream>>>(attnb, wob, out, INNER_DIM, DMODEL, 0, 0, 0);
}

// Round 7
// 284.603 us; speedup vs baseline: 1.1361x; 1.1286x over previous
//
#include <hip/hip_runtime.h>
#include <hip/hip_bf16.h>
#include <cstdint>
#include <cstddef>

// Problem constants
#define S_LEN 2048
#define DMODEL 2048
#define NHEADS 8
#define DHEAD 128
#define INNER_DIM 1024
#define BATCH 2

typedef __bf16 bf16;
typedef __bf16 bf16x8 __attribute__((ext_vector_type(8)));
typedef __bf16 bf16x4 __attribute__((ext_vector_type(4)));
typedef float f32x4 __attribute__((ext_vector_type(4)));

__device__ __forceinline__ void gload_lds16(const void* g, void* l) {
  __builtin_amdgcn_global_load_lds(
      (const __attribute__((address_space(1))) void*)g,
      (__attribute__((address_space(3))) void*)l, 16, 0, 0);
}

__device__ __forceinline__ float sigmoidf_(float x) {
  return 1.0f / (1.0f + expf(-x));
}

// ---------------------------------------------------------------------------
// Convert fp32 weights -> bf16 (Wq, Wk, Wv laid out contiguously, then Wo).
// ---------------------------------------------------------------------------
__global__ __launch_bounds__(256) void convert_w_kernel(
    const float* __restrict__ wq, const float* __restrict__ wk,
    const float* __restrict__ wv, const float* __restrict__ wo,
    bf16* __restrict__ wqkvb, bf16* __restrict__ wob) {
  size_t i4 = ((size_t)blockIdx.x * 256 + threadIdx.x) * 4;
  const float* src;
  bf16* dst;
  size_t off;
  if (i4 < 2097152UL)       { src = wq; dst = wqkvb;           off = i4; }
  else if (i4 < 4194304UL)  { src = wk; dst = wqkvb + 2097152; off = i4 - 2097152UL; }
  else if (i4 < 6291456UL)  { src = wv; dst = wqkvb + 4194304; off = i4 - 4194304UL; }
  else                      { src = wo; dst = wob;             off = i4 - 6291456UL; }
  float4 v = *(const float4*)(src + off);
  bf16x4 o;
  o[0] = (bf16)v.x; o[1] = (bf16)v.y; o[2] = (bf16)v.z; o[3] = (bf16)v.w;
  *(bf16x4*)(dst + off) = o;
}

// ---------------------------------------------------------------------------
// Per-head alpha.
// ---------------------------------------------------------------------------
__global__ __launch_bounds__(64) void alpha_kernel(
    const float* __restrict__ alpha_log, float* __restrict__ la_mean,
    float* __restrict__ la_d) {
  int h = blockIdx.x;
  int lane = threadIdx.x;
  float a1 = sigmoidf_(alpha_log[h * 128 + lane]);
  float a2 = sigmoidf_(alpha_log[h * 128 + 64 + lane]);
  la_d[h * 128 + lane] = logf(a1);
  la_d[h * 128 + 64 + lane] = logf(a2);
  float s = a1 + a2;
  for (int off = 32; off; off >>= 1) s += __shfl_down(s, off);
  if (lane == 0) la_mean[h] = logf(fmaxf(s * (1.0f / 128.0f), 1e-6f));
}

// ---------------------------------------------------------------------------
// beta[n,h] = sigmoid(x[n,:].Wb[h,:] + bb[h]); also emits xb = bf16(x).
// ---------------------------------------------------------------------------
__global__ __launch_bounds__(64) void beta_xb_kernel(
    const float* __restrict__ x, const float* __restrict__ Wb,
    const float* __restrict__ bbias, float* __restrict__ beta,
    bf16* __restrict__ xb) {
  int n = blockIdx.x;
  int lane = threadIdx.x;
  float acc[8];
#pragma unroll
  for (int h = 0; h < 8; h++) acc[h] = 0.0f;
  const float4* x4 = (const float4*)(x + (size_t)n * DMODEL);
  bf16* xbr = xb + (size_t)n * DMODEL;
  for (int d4 = lane; d4 < DMODEL / 4; d4 += 64) {
    float4 xv = x4[d4];
    bf16x4 o;
    o[0] = (bf16)xv.x; o[1] = (bf16)xv.y; o[2] = (bf16)xv.z; o[3] = (bf16)xv.w;
    *(bf16x4*)(xbr + d4 * 4) = o;
#pragma unroll
    for (int h = 0; h < 8; h++) {
      float4 wv = ((const float4*)(Wb + (size_t)h * DMODEL))[d4];
      acc[h] += xv.x * wv.x + xv.y * wv.y + xv.z * wv.z + xv.w * wv.w;
    }
  }
#pragma unroll
  for (int off = 32; off; off >>= 1)
#pragma unroll
    for (int h = 0; h < 8; h++) acc[h] += __shfl_down(acc[h], off);
  if (lane == 0) {
#pragma unroll
    for (int h = 0; h < 8; h++)
      beta[(size_t)n * 8 + h] = sigmoidf_(acc[h] + bbias[h]);
  }
}

// ---------------------------------------------------------------------------
// bf16 NT GEMM (round-3 config: BK=32, XOR bank swizzle, XCD tile swizzle).
// For z==2 (the V projection) the epilogue ALSO writes a transposed copy
// vt[((b*8+h)*128+e)*2048 + s] consumed by the MFMA attention kernel.
// obf: 1 -> store bf16, 0 -> store f32.
// ---------------------------------------------------------------------------
__global__ __launch_bounds__(256) void gemm_bt_kernel(
    const bf16* __restrict__ A, const bf16* __restrict__ Bm, void* Cv, int K,
    int N, size_t strideB, size_t strideC, int obf, bf16* __restrict__ vt) {
  // ---- XCD-aware tile remap (bijective) ----
  const int id = blockIdx.x + gridDim.x * (blockIdx.y + gridDim.y * blockIdx.z);
  const int xcd = id & 7;
  const int s = id >> 3;
  const int xs = gridDim.x >> 2;
  const int ys = gridDim.y >> 1;
  const int perz = xs * ys;
  const int z = s / perz;
  const int r = s - z * perz;
  const int tx = (xcd & 3) * xs + (r % xs);
  const int ty = (xcd >> 2) * ys + (r / xs);
  const int tile_n = tx * 128;
  const int tile_m = ty * 128;

  const bf16* Bp = Bm + (size_t)z * strideB;
  const int tid = threadIdx.x;
  const int lane = tid & 63;
  const int wv = tid >> 6;

  __shared__ bf16 As[128 * 32];
  __shared__ bf16 Bs[128 * 32];

  f32x4 acc[4][4];
#pragma unroll
  for (int i = 0; i < 4; i++)
#pragma unroll
    for (int j = 0; j < 4; j++) acc[i][j] = (f32x4){0.f, 0.f, 0.f, 0.f};

  const int wm = (wv >> 1) * 64;
  const int wn = (wv & 1) * 64;
  const int lr = lane & 15;
  const int kq = lane >> 4;
  const int swzA = ((wm + lr) >> 1) & 3;
  const int swzB = ((wn + lr) >> 1) & 3;
  const int kA = (kq ^ swzA) * 8;
  const int kB = (kq ^ swzB) * 8;

  const int ar = wv * 32 + (lane >> 2);
  const int g = ((lane & 3) ^ ((ar >> 1) & 3)) * 8;
  const bf16* Ag = A + (size_t)(tile_m + ar) * K + g;
  const bf16* Bg = Bp + (size_t)(tile_n + ar) * K + g;
  bf16* AsW = &As[wv * 1024];
  bf16* BsW = &Bs[wv * 1024];

  for (int k0 = 0; k0 < K; k0 += 32) {
    gload_lds16(Ag + k0, AsW);
    gload_lds16(Ag + (size_t)16 * K + k0, AsW + 512);
    gload_lds16(Bg + k0, BsW);
    gload_lds16(Bg + (size_t)16 * K + k0, BsW + 512);
    __syncthreads();
    bf16x8 af[4], bfr[4];
#pragma unroll
    for (int mi = 0; mi < 4; mi++)
      af[mi] = *(const bf16x8*)&As[(wm + mi * 16 + lr) * 32 + kA];
#pragma unroll
    for (int ni = 0; ni < 4; ni++)
      bfr[ni] = *(const bf16x8*)&Bs[(wn + ni * 16 + lr) * 32 + kB];
#pragma unroll
    for (int mi = 0; mi < 4; mi++)
#pragma unroll
      for (int ni = 0; ni < 4; ni++)
        acc[mi][ni] = __builtin_amdgcn_mfma_f32_16x16x32_bf16(
            af[mi], bfr[ni], acc[mi][ni], 0, 0, 0);
    __syncthreads();
  }

  const int crow0 = tile_m + wm + (lane >> 4) * 4;
  const int ccol = tile_n + wn + (lane & 15);
  if (obf) {
    bf16* Cb = (bf16*)Cv + (size_t)z * strideC;
#pragma unroll
    for (int mi = 0; mi < 4; mi++)
#pragma unroll
      for (int ni = 0; ni < 4; ni++)
#pragma unroll
        for (int r2 = 0; r2 < 4; r2++)
          Cb[(size_t)(crow0 + mi * 16 + r2) * N + ccol + ni * 16] =
              (bf16)acc[mi][ni][r2];
    if (z == 2) {
      // transposed copy for attention's PV B-fragments
#pragma unroll
      for (int mi = 0; mi < 4; mi++) {
        int row0 = crow0 + mi * 16;
        int bb2 = row0 >> 11, ss = row0 & 2047;
#pragma unroll
        for (int ni = 0; ni < 4; ni++) {
          int col = ccol + ni * 16;
          bf16x4 o4;
#pragma unroll
          for (int r2 = 0; r2 < 4; r2++) o4[r2] = (bf16)acc[mi][ni][r2];
          *(bf16x4*)&vt[(((size_t)bb2 * 8 + (col >> 7)) * 128 + (col & 127)) *
                            2048 +
                        ss] = o4;
        }
      }
    }
  } else {
    float* Cf = (float*)Cv + (size_t)z * strideC;
#pragma unroll
    for (int mi = 0; mi < 4; mi++)
#pragma unroll
      for (int ni = 0; ni < 4; ni++)
#pragma unroll
        for (int r2 = 0; r2 < 4; r2++)
          Cf[(size_t)(crow0 + mi * 16 + r2) * N + ccol + ni * 16] =
              acc[mi][ni][r2];
  }
}

// ---------------------------------------------------------------------------
// RoPE in place on bf16 q and k.
// ---------------------------------------------------------------------------
__global__ __launch_bounds__(256) void rope_kernel(bf16* __restrict__ q,
                                                   bf16* __restrict__ k) {
  int idx = blockIdx.x * 256 + threadIdx.x;  // < 524288
  int j0 = (idx & 15) * 4;
  int nh = idx >> 4;  // n*8 + h, n < 4096
  int s = (nh >> 3) & (S_LEN - 1);
  size_t base = (size_t)nh * 128 + j0;
  bf16x4 qa = *(bf16x4*)&q[base], qb = *(bf16x4*)&q[base + 64];
  bf16x4 ka = *(bf16x4*)&k[base], kb = *(bf16x4*)&k[base + 64];
#pragma unroll
  for (int jj = 0; jj < 4; jj++) {
    float inv = expf(-(float)(j0 + jj) * (9.210340371976184f / 64.0f));
    float f = (float)s * inv;
    float sn, c;
    sincosf(f, &sn, &c);
    float q1 = (float)qa[jj], q2 = (float)qb[jj];
    qa[jj] = (bf16)(q1 * c - q2 * sn);
    qb[jj] = (bf16)(q2 * c + q1 * sn);
    float k1 = (float)ka[jj], k2 = (float)kb[jj];
    ka[jj] = (bf16)(k1 * c - k2 * sn);
    kb[jj] = (bf16)(k2 * c + k1 * sn);
  }
  *(bf16x4*)&q[base] = qa;
  *(bf16x4*)&q[base + 64] = qb;
  *(bf16x4*)&k[base] = ka;
  *(bf16x4*)&k[base + 64] = kb;
}

// ---------------------------------------------------------------------------
// MFMA banded-decay attention. One block per (s-block 64, h, b); 4 waves,
// each wave owns 16 q rows. QK^T and PV via 16x16x32 bf16 MFMA.
// Q/K fragments come straight from global (rows contiguous); V comes from the
// transposed vt buffer; P transits a wave-private LDS buffer (C->A layout).
// ---------------------------------------------------------------------------
__global__ __launch_bounds__(256) void attn_mfma_kernel(
    const bf16* __restrict__ q, const bf16* __restrict__ k,
    const bf16* __restrict__ vt, const float* __restrict__ beta,
    const float* __restrict__ la_mean, bf16* __restrict__ outb) {
  const int s0 = blockIdx.x * 64;
  const int h = blockIdx.y;
  const int b = blockIdx.z;
  const int tid = threadIdx.x;
  const int w = tid >> 6;
  const int lane = tid & 63;
  const int lr = lane & 15;
  const int kq = lane >> 4;  // quad
  const float la = la_mean[h];

  __shared__ __align__(16) bf16 Ps[4][2][16][72];

  // Q A-fragments (reused across both K-tiles): row sg+lr, d = ks*32+kq*8
  const int sg = s0 + w * 16;
  const size_t qbase =
      ((size_t)b * S_LEN + (sg + lr)) * INNER_DIM + h * 128 + kq * 8;
  bf16x8 aq[4];
#pragma unroll
  for (int ks = 0; ks < 4; ks++)
    aq[ks] = *(const bf16x8*)&q[qbase + ks * 32];

  f32x4 O[8];
#pragma unroll
  for (int en = 0; en < 8; en++) O[en] = (f32x4){0.f, 0.f, 0.f, 0.f};

  const size_t kbase = (size_t)b * S_LEN * INNER_DIM + h * 128 + kq * 8;
  const size_t vtbase = ((size_t)b * 8 + h) * 128 * 2048;

#pragma unroll
  for (int tile = 0; tile < 2; tile++) {
    const int tb = s0 - 64 + tile * 64;
    // ---- scores: 4 n-tiles of 16 t's, K'=128 in 4 steps ----
    f32x4 sc[4];
#pragma unroll
    for (int nt = 0; nt < 4; nt++) sc[nt] = (f32x4){0.f, 0.f, 0.f, 0.f};
#pragma unroll
    for (int nt = 0; nt < 4; nt++) {
      int t = tb + nt * 16 + lr;
      int tc = t > 0 ? t : 0;
#pragma unroll
      for (int ks = 0; ks < 4; ks++) {
        bf16x8 bk = *(const bf16x8*)&k[kbase + (size_t)tc * INNER_DIM + ks * 32];
        sc[nt] = __builtin_amdgcn_mfma_f32_16x16x32_bf16(aq[ks], bk, sc[nt],
                                                         0, 0, 0);
      }
    }
    // ---- weights -> P (bf16) in wave-private LDS ----
#pragma unroll
    for (int nt = 0; nt < 4; nt++) {
      int t = tb + nt * 16 + lr;  // this lane's column (C-layout col=lane&15)
      int tc = t > 0 ? t : 0;
      float bt = beta[((size_t)b * S_LEN + tc) * 8 + h];
#pragma unroll
      for (int reg = 0; reg < 4; reg++) {
        int qrow = sg + kq * 4 + reg;  // C-layout row = quad*4+reg
        int td = qrow - t;
        float wgt = 0.0f;
        if (t >= 0 && td >= 0 && td < 64)
          wgt = sc[nt][reg] * __expf((float)td * la) * bt;
        Ps[w][tile][kq * 4 + reg][nt * 16 + lr] = (bf16)wgt;
      }
    }
    __syncthreads();
    // ---- PV: P(16x64) x V(64x128) -> O(16x128) ----
    bf16x8 ap[2];
#pragma unroll
    for (int ks2 = 0; ks2 < 2; ks2++)
      ap[ks2] = *(const bf16x8*)&Ps[w][tile][lr][ks2 * 32 + kq * 8];
#pragma unroll
    for (int en = 0; en < 8; en++) {
#pragma unroll
      for (int ks2 = 0; ks2 < 2; ks2++) {
        int t0f = tb + ks2 * 32 + kq * 8;
        int tcf = t0f > 0 ? t0f : 0;  // clamped; P==0 masks any garbage
        bf16x8 bv = *(const bf16x8*)&vt[vtbase + (size_t)(en * 16 + lr) * 2048 +
                                        tcf];
        O[en] = __builtin_amdgcn_mfma_f32_16x16x32_bf16(ap[ks2], bv, O[en], 0,
                                                        0, 0);
      }
    }
  }
  // ---- epilogue: O C-layout -> attnb bf16 ----
  const size_t obase = (size_t)b * S_LEN * INNER_DIM + h * 128;
#pragma unroll
  for (int en = 0; en < 8; en++) {
#pragma unroll
    for (int reg = 0; reg < 4; reg++) {
      int qrow = sg + kq * 4 + reg;
      outb[obase + (size_t)qrow * INNER_DIM + en * 16 + lr] =
          (bf16)O[en][reg];
    }
  }
}

// ---------------------------------------------------------------------------
// Stage 1: partial state per 32-step chunk (bf16 k/v inputs), no atomics.
// ---------------------------------------------------------------------------
__global__ __launch_bounds__(256) void state_partial_kernel(
    const bf16* __restrict__ k, const bf16* __restrict__ v,
    const float* __restrict__ beta, const float* __restrict__ la_d,
    float* __restrict__ part) {
  const int bh = blockIdx.x;
  const int chunk = blockIdx.y;
  const int b = bh >> 3, h = bh & 7;
  const int t0 = S_LEN - 512 + chunk * 32;
  const int tid = threadIdx.x;
  const int d = tid >> 1;
  const int eh = (tid & 1) * 64;

  __shared__ float ks[32][128];
  __shared__ float vsm[32][128];
  __shared__ float bs[32];

  const size_t bh_off = ((size_t)b * S_LEN) * INNER_DIM + (size_t)h * 128;
  for (int u = tid; u < 32 * 16; u += 256) {
    int r = u >> 4, c8 = (u & 15) * 8;
    bf16x8 kv = *(const bf16x8*)&k[bh_off + (size_t)(t0 + r) * INNER_DIM + c8];
    bf16x8 vv = *(const bf16x8*)&v[bh_off + (size_t)(t0 + r) * INNER_DIM + c8];
#pragma unroll
    for (int j = 0; j < 8; j++) {
      ks[r][c8 + j] = (float)kv[j];
      vsm[r][c8 + j] = (float)vv[j];
    }
  }
  if (tid < 32) bs[tid] = beta[((size_t)b * S_LEN + t0 + tid) * 8 + h];
  __syncthreads();

  const float lad = la_d[h * 128 + d];
  float acc[64];
#pragma unroll
  for (int e = 0; e < 64; e++) acc[e] = 0.0f;

  for (int tl = 0; tl < 32; tl++) {
    int m = (S_LEN - 1) - (t0 + tl);
    float f = __expf((float)m * lad);
    float coef = bs[tl] * ks[tl][d] * f;
    if (coef != 0.0f) {
#pragma unroll
      for (int e = 0; e < 64; e += 4) {
        float4 vv = *(const float4*)&vsm[tl][eh + e];
        acc[e + 0] = fmaf(coef, vv.x, acc[e + 0]);
        acc[e + 1] = fmaf(coef, vv.y, acc[e + 1]);
        acc[e + 2] = fmaf(coef, vv.z, acc[e + 2]);
        acc[e + 3] = fmaf(coef, vv.w, acc[e + 3]);
      }
    }
  }
  float* pp = part + (((size_t)chunk * 16 + bh) * 16384 + (size_t)d * 128 + eh);
#pragma unroll
  for (int e = 0; e < 64; e += 4) {
    float4 o = {acc[e + 0], acc[e + 1], acc[e + 2], acc[e + 3]};
    *(float4*)&pp[e] = o;
  }
}

// ---------------------------------------------------------------------------
// Stage 2: sum the 16 chunk partials into the final state.
// ---------------------------------------------------------------------------
__global__ __launch_bounds__(256) void state_reduce_kernel(
    const float* __restrict__ part, float* __restrict__ state) {
  size_t off = ((size_t)blockIdx.x * 256 + threadIdx.x) * 4;
  float4 s = {0.f, 0.f, 0.f, 0.f};
#pragma unroll
  for (int c = 0; c < 16; c++) {
    float4 p = *(const float4*)&part[(size_t)c * 262144 + off];
    s.x += p.x; s.y += p.y; s.z += p.z; s.w += p.w;
  }
  *(float4*)&state[off] = s;
}

// ---------------------------------------------------------------------------
extern "C" void kernel_launch(void* const* d_in, const int* in_sizes, int n_in,
                              void* d_out, int out_size, void* d_ws,
                              size_t ws_size, hipStream_t stream) {
  const float* x = (const float*)d_in[0];
  const float* Wq = (const float*)d_in[1];
  const float* Wk = (const float*)d_in[2];
  const float* Wv = (const float*)d_in[3];
  const float* Wo = (const float*)d_in[4];
  const float* Wb = (const float*)d_in[5];
  const float* bb = (const float*)d_in[6];
  const float* alog = (const float*)d_in[7];
  float* out = (float*)d_out;

  char* ws = (char*)d_ws;
  bf16* xb = (bf16*)(ws);                      // 16 MB
  float* part = (float*)(ws);                  // reuses xb after QKV GEMM
  bf16* wqkvb = (bf16*)(ws + 16777216UL);      // 12 MB
  bf16* wob = (bf16*)(ws + 29360128UL);        // 4 MB
  bf16* q = (bf16*)(ws + 33554432UL);          // 8 MB
  bf16* kk = (bf16*)(ws + 41943040UL);         // 8 MB
  bf16* vv = (bf16*)(ws + 50331648UL);         // 8 MB
  bf16* attnb = (bf16*)(ws + 58720256UL);      // 8 MB
  bf16* vt = (bf16*)(ws + 67108864UL);         // 8 MB (V transposed)
  float* beta = (float*)(ws + 75497472UL);     // 128 KB
  float* la_mean = (float*)(ws + 75628544UL);  // 32 B
  float* la_d = (float*)(ws + 75628800UL);     // 4 KB

  convert_w_kernel<<<8192, 256, 0, stream>>>(Wq, Wk, Wv, Wo, wqkvb, wob);
  alpha_kernel<<<8, 64, 0, stream>>>(alog, la_mean, la_d);
  beta_xb_kernel<<<BATCH * S_LEN, 64, 0, stream>>>(x, Wb, bb, beta, xb);
  // fused QKV GEMM -> bf16 q/kk/vv (+ vt transposed copy of v)
  gemm_bt_kernel<<<dim3(INNER_DIM / 128, (BATCH * S_LEN) / 128, 3), 256, 0,
                   stream>>>(xb, wqkvb, q, DMODEL, INNER_DIM, 2097152UL,
                             4194304UL, 1, vt);
  rope_kernel<<<2048, 256, 0, stream>>>(q, kk);
  attn_mfma_kernel<<<dim3(S_LEN / 64, NHEADS, BATCH), 256, 0, stream>>>(
      q, kk, vt, beta, la_mean, attnb);
  state_partial_kernel<<<dim3(16, 16), 256, 0, stream>>>(kk, vv, beta, la_d,
                                                         part);
  state_reduce_kernel<<<256, 256, 0, stream>>>(part, out + 8388608);
  gemm_bt_kernel<<<dim3(DMODEL / 128, (BATCH * S_LEN) / 128, 1), 256, 0,
                   stream>>>(attnb, wob, out, INNER_DIM, DMODEL, 0, 0, 0,
                             nullptr);
}